// Round 5
// baseline (500.347 us; speedup 1.0000x reference)
//
#include <hip/hip_runtime.h>

typedef __bf16 bf16;
typedef __bf16 bf16x4 __attribute__((ext_vector_type(4)));
typedef __bf16 bf16x8 __attribute__((ext_vector_type(8)));
typedef float  f32x4  __attribute__((ext_vector_type(4)));

#define B_ 2048
#define T_ 128
#define C_ 256
#define H_ 64

// LDS layout (bytes):
//  Qs[128][72] @0 (18432), Ks[128][72] @18432 (18432), Vt[64][136] @36864 (17408)
//  Ps[128][136] @0 (34816) — aliases Qs/Ks after all S-phase reads complete
// high-water 54272; 3 blocks/CU: 3*54272 = 162816 <= 163840 -> 12 waves/CU
// (x is NOT staged: each x element feeds exactly one A-fragment lane -> zero reuse,
//  so A-fragments are loaded directly from global with in-register fp32->bf16 cvt)
#define SMEM_BYTES 54272

__global__ void wt_kernel(const float* __restrict__ Wk, const float* __restrict__ Wq,
                          const float* __restrict__ Wv, bf16* __restrict__ Wt) {
    int o = blockIdx.x * 256 + threadIdx.x;     // 0..49151
    int slot = o >> 14;
    int r    = o & 16383;                       // coalesced source read
    int cc   = r >> 6;
    int h    = r & 63;
    const float* src = (slot == 0) ? Wq : (slot == 1 ? Wk : Wv);
    Wt[slot * 16384 + h * 256 + cc] = (bf16)src[r];
}

__global__ void __launch_bounds__(256, 3)
attn_kernel(const float* __restrict__ xg, const bf16* __restrict__ Wt,
            float* __restrict__ outg) {
    __shared__ __align__(16) char smem_raw[SMEM_BYTES];
    bf16* Qs  = (bf16*)smem_raw;                 // [128][72]
    bf16* Ks  = (bf16*)(smem_raw + 18432);       // [128][72]
    bf16* Vt  = (bf16*)(smem_raw + 36864);       // [64][136]
    bf16* Ps  = (bf16*)smem_raw;                 // [128][136]

    const int tid  = threadIdx.x;
    const int b    = blockIdx.x;
    const int w    = tid >> 6;
    const int lane = tid & 63;
    const int quad = lane >> 4;
    const int n16  = lane & 15;

    const f32x4 zero4 = {0.f, 0.f, 0.f, 0.f};
    const float*  xbp = xg + (size_t)b * (T_ * C_);
    const ushort* WtU = (const ushort*)Wt;

    // ---------------- phase 1: projections, K=256, A-fragments direct from global ----------------
    f32x4 acc[2][12];
    #pragma unroll
    for (int mt = 0; mt < 2; mt++)
        #pragma unroll
        for (int nt = 0; nt < 12; nt++) acc[mt][nt] = zero4;

    #pragma unroll
    for (int ks = 0; ks < 8; ks++) {
        bf16x8 a[2];
        #pragma unroll
        for (int mt = 0; mt < 2; mt++) {
            const float* ap = xbp + (16 * (2 * w + mt) + n16) * C_ + ks * 32 + 8 * quad;
            float4 a0 = *(const float4*)(ap);
            float4 a1 = *(const float4*)(ap + 4);
            bf16x8 av = {(bf16)a0.x, (bf16)a0.y, (bf16)a0.z, (bf16)a0.w,
                         (bf16)a1.x, (bf16)a1.y, (bf16)a1.z, (bf16)a1.w};
            a[mt] = av;
        }
        #pragma unroll
        for (int nt = 0; nt < 12; nt++) {
            // B-fragments from global Wt (96 KB, L2-resident, shared by all blocks)
            const ushort* wp = WtU + (nt >> 2) * 16384 + (16 * (nt & 3) + n16) * 256 + ks * 32 + 8 * quad;
            bf16x8 bfr = *(const bf16x8*)wp;
            acc[0][nt] = __builtin_amdgcn_mfma_f32_16x16x32_bf16(a[0], bfr, acc[0][nt], 0, 0, 0);
            acc[1][nt] = __builtin_amdgcn_mfma_f32_16x16x32_bf16(a[1], bfr, acc[1][nt], 0, 0, 0);
        }
    }

    // write Q[t][h] (pre-scaled by C^-0.5 = 2^-4, exact in bf16), K[s][h], Vt[h][t]
    // first LDS use in the kernel -> no barrier needed before these writes
    #pragma unroll
    for (int mt = 0; mt < 2; mt++) {
        int tbase = 16 * (2 * w + mt) + 4 * quad;
        #pragma unroll
        for (int nt = 0; nt < 4; nt++) {         // Q, scaled
            int h = 16 * nt + n16;
            #pragma unroll
            for (int r = 0; r < 4; r++)
                Qs[(tbase + r) * 72 + h] = (bf16)(acc[mt][nt][r] * 0.0625f);
        }
        #pragma unroll
        for (int nt = 4; nt < 8; nt++) {         // K
            int h = 16 * (nt & 3) + n16;
            #pragma unroll
            for (int r = 0; r < 4; r++)
                Ks[(tbase + r) * 72 + h] = (bf16)acc[mt][nt][r];
        }
        #pragma unroll
        for (int nt = 8; nt < 12; nt++) {        // V transposed: Vt[h][t]
            int h = 16 * (nt - 8) + n16;
            bf16x4 pv = {(bf16)acc[mt][nt][0], (bf16)acc[mt][nt][1],
                         (bf16)acc[mt][nt][2], (bf16)acc[mt][nt][3]};
            *(bf16x4*)(Vt + h * 136 + tbase) = pv;
        }
    }
    __syncthreads();                             // (1) Q/K/V visible to all waves

    // ---------------- S = Q K^T, causal softmax ----------------
    f32x4 sacc[2][8];
    int mts[2] = {w, 7 - w};
    #pragma unroll
    for (int half = 0; half < 2; half++) {
        int mt = mts[half];
        int sT = ((mt >> 1) + 1) * 2;
        bf16x8 qa[2];
        #pragma unroll
        for (int ks = 0; ks < 2; ks++)
            qa[ks] = *(const bf16x8*)(Qs + (16 * mt + n16) * 72 + 32 * ks + 8 * quad);
        #pragma unroll
        for (int nt = 0; nt < 8; nt++) {
            sacc[half][nt] = zero4;
            if (nt < sT) {
                bf16x8 kb0 = *(const bf16x8*)(Ks + (16 * nt + n16) * 72 + 8 * quad);
                bf16x8 kb1 = *(const bf16x8*)(Ks + (16 * nt + n16) * 72 + 32 + 8 * quad);
                sacc[half][nt] = __builtin_amdgcn_mfma_f32_16x16x32_bf16(qa[0], kb0, sacc[half][nt], 0, 0, 0);
                sacc[half][nt] = __builtin_amdgcn_mfma_f32_16x16x32_bf16(qa[1], kb1, sacc[half][nt], 0, 0, 0);
            }
        }
        #pragma unroll
        for (int r = 0; r < 4; r++) {
            int t = 16 * mt + 4 * quad + r;
            float mx = -3.0e38f;
            #pragma unroll
            for (int nt = 0; nt < 8; nt++) {
                if (nt < sT) {
                    float v = sacc[half][nt][r];                 // already C^-0.5-scaled
                    v = (16 * nt + n16 <= t) ? v : -3.0e38f;     // causal
                    sacc[half][nt][r] = v;
                    mx = fmaxf(mx, v);
                }
            }
            mx = fmaxf(mx, __shfl_xor(mx, 1));
            mx = fmaxf(mx, __shfl_xor(mx, 2));
            mx = fmaxf(mx, __shfl_xor(mx, 4));
            mx = fmaxf(mx, __shfl_xor(mx, 8));
            float sum = 0.f;
            #pragma unroll
            for (int nt = 0; nt < 8; nt++) {
                if (nt < sT) {
                    float p = __builtin_amdgcn_exp2f((sacc[half][nt][r] - mx) * 1.4426950408889634f);
                    sacc[half][nt][r] = p;
                    sum += p;
                }
            }
            sum += __shfl_xor(sum, 1);
            sum += __shfl_xor(sum, 2);
            sum += __shfl_xor(sum, 4);
            sum += __shfl_xor(sum, 8);
            float rinv = 1.0f / sum;
            #pragma unroll
            for (int nt = 0; nt < 8; nt++)
                if (nt < sT) sacc[half][nt][r] *= rinv;
        }
    }
    __syncthreads();                             // (2) all Q/K reads done; Ps may alias

    #pragma unroll
    for (int half = 0; half < 2; half++) {
        int mt = mts[half];
        int sT = ((mt >> 1) + 1) * 2;
        #pragma unroll
        for (int nt = 0; nt < 8; nt++) {
            if (nt < sT) {
                #pragma unroll
                for (int r = 0; r < 4; r++)
                    Ps[(16 * mt + 4 * quad + r) * 136 + 16 * nt + n16] = (bf16)sacc[half][nt][r];
            }
        }
    }
    __syncthreads();                             // (3) Ps visible

    // ---------------- O = P V, direct global store ----------------
    f32x4 oacc[2][4];
    #pragma unroll
    for (int half = 0; half < 2; half++) {
        int mt  = mts[half];
        int kst = (mt >> 1) + 1;
        #pragma unroll
        for (int nt = 0; nt < 4; nt++) oacc[half][nt] = zero4;
        #pragma unroll
        for (int ks = 0; ks < 4; ks++) {
            if (ks < kst) {
                bf16x8 pa = *(const bf16x8*)(Ps + (16 * mt + n16) * 136 + 32 * ks + 8 * quad);
                #pragma unroll
                for (int nt = 0; nt < 4; nt++) {
                    bf16x8 vb = *(const bf16x8*)(Vt + (16 * nt + n16) * 136 + 32 * ks + 8 * quad);
                    oacc[half][nt] = __builtin_amdgcn_mfma_f32_16x16x32_bf16(pa, vb, oacc[half][nt], 0, 0, 0);
                }
            }
        }
    }
    // C-layout: row = 4*quad + r, col = 16*nt + n16 -> 4 x 64B sectors per store instr
    #pragma unroll
    for (int half = 0; half < 2; half++) {
        int mt = mts[half];
        float* ob = outg + ((size_t)b * T_ + 16 * mt + 4 * quad) * H_;
        #pragma unroll
        for (int nt = 0; nt < 4; nt++)
            #pragma unroll
            for (int r = 0; r < 4; r++)
                ob[r * H_ + 16 * nt + n16] = oacc[half][nt][r];
    }
}

extern "C" void kernel_launch(void* const* d_in, const int* in_sizes, int n_in,
                              void* d_out, int out_size, void* d_ws, size_t ws_size,
                              hipStream_t stream) {
    const float* x  = (const float*)d_in[0];
    const float* Wk = (const float*)d_in[1];
    const float* Wq = (const float*)d_in[2];
    const float* Wv = (const float*)d_in[3];
    bf16* Wt = (bf16*)d_ws;                      // 98304 B scratch
    wt_kernel<<<192, 256, 0, stream>>>(Wk, Wq, Wv, Wt);
    attn_kernel<<<B_, 256, 0, stream>>>(x, Wt, (float*)d_out);
}